// Round 5
// baseline (920.765 us; speedup 1.0000x reference)
//
#include <hip/hip_runtime.h>

#define N_SAMPLES 131072
#define N_CLASSES 1000
#define BINS 10

// d_ws layout:
//   [0, N_SAMPLES) floats            : values[i] = -log_softmax(pred_i)[t_i]
//   at N_SAMPLES (as uint*) slot 0   : vmax bits (atomicMax on uint; values>=0)
//   slots 1..10                      : counts[10] (uint)
//   slots 11..20                     : sums[10] (float)
//   slot 21                          : done counter (last-block pattern)

__global__ __launch_bounds__(256) void values_kernel(const float* __restrict__ pred,
                                                     const int* __restrict__ target,
                                                     float* __restrict__ values,
                                                     unsigned int* __restrict__ vmax_bits) {
    __shared__ float smax[4];
    const int wave = threadIdx.x >> 6;   // 4 waves per block, 1 row per wave
    const int lane = threadIdx.x & 63;
    const int row = blockIdx.x * 4 + wave;   // grid == N_SAMPLES/4 exactly

    const float4* __restrict__ rp = (const float4*)(pred + (size_t)row * N_CLASSES);

    // All four 16B loads issue unconditionally; row has exactly 250 float4.
    // k=0..2 always in-range; k=3 tail clamps the address, values masked -INF.
    float4 r0 = rp[lane];
    float4 r1 = rp[64 + lane];
    float4 r2 = rp[128 + lane];
    const int i3 = (192 + lane < 250) ? (192 + lane) : 249;
    float4 r3 = rp[i3];

    // Target logit: wave-uniform address -> broadcast, hidden under row loads.
    const int t = target[row];
    const float xt = pred[(size_t)row * N_CLASSES + t];

    const bool v3 = (192 + lane) < 250;
    const float NEG_INF = -INFINITY;
    float r3x = v3 ? r3.x : NEG_INF;
    float r3y = v3 ? r3.y : NEG_INF;
    float r3z = v3 ? r3.z : NEG_INF;
    float r3w = v3 ? r3.w : NEG_INF;

    float m0 = fmaxf(fmaxf(r0.x, r0.y), fmaxf(r0.z, r0.w));
    float m1 = fmaxf(fmaxf(r1.x, r1.y), fmaxf(r1.z, r1.w));
    float m2 = fmaxf(fmaxf(r2.x, r2.y), fmaxf(r2.z, r2.w));
    float m3 = fmaxf(fmaxf(r3x, r3y), fmaxf(r3z, r3w));
    float lmax = fmaxf(fmaxf(m0, m1), fmaxf(m2, m3));
#pragma unroll
    for (int off = 32; off > 0; off >>= 1)
        lmax = fmaxf(lmax, __shfl_xor(lmax, off, 64));

    float s0 = __expf(r0.x - lmax) + __expf(r0.y - lmax) +
               __expf(r0.z - lmax) + __expf(r0.w - lmax);
    float s1 = __expf(r1.x - lmax) + __expf(r1.y - lmax) +
               __expf(r1.z - lmax) + __expf(r1.w - lmax);
    float s2 = __expf(r2.x - lmax) + __expf(r2.y - lmax) +
               __expf(r2.z - lmax) + __expf(r2.w - lmax);
    float s3 = __expf(r3x - lmax) + __expf(r3y - lmax) +
               __expf(r3z - lmax) + __expf(r3w - lmax);
    float s = (s0 + s1) + (s2 + s3);
#pragma unroll
    for (int off = 32; off > 0; off >>= 1)
        s += __shfl_xor(s, off, 64);

    if (lane == 0) {
        float val = logf(s) + lmax - xt;   // logsumexp - x_t  (>= 0 always)
        values[row] = val;
        smax[wave] = val;
    }
    __syncthreads();
    // Fused global-max: one fire-and-forget atomic per block (32768 total;
    // no wave stall -- no return value consumed).
    if (threadIdx.x == 0) {
        float bm = fmaxf(fmaxf(smax[0], smax[1]), fmaxf(smax[2], smax[3]));
        atomicMax(vmax_bits, __float_as_uint(bm));  // valid: non-negative floats
    }
}

__global__ __launch_bounds__(256) void hist_kernel(const float* __restrict__ values,
                                                   const unsigned int* __restrict__ vmax_bits,
                                                   unsigned int* __restrict__ counts,
                                                   float* __restrict__ sums,
                                                   unsigned int* __restrict__ done,
                                                   float* __restrict__ out) {
    __shared__ unsigned int lc[BINS];
    __shared__ float ls[BINS];
    __shared__ bool amLast;
    if (threadIdx.x < BINS) { lc[threadIdx.x] = 0u; ls[threadIdx.x] = 0.f; }
    __syncthreads();

    const float vmax = __uint_as_float(*vmax_bits);
    float edges[BINS + 1];
#pragma unroll
    for (int j = 0; j <= BINS; ++j) edges[j] = (float)j / 10.0f;  // match jnp.arange/10
    edges[BINS] += 1e-6f;

    for (int i = blockIdx.x * blockDim.x + threadIdx.x; i < N_SAMPLES;
         i += gridDim.x * blockDim.x) {
        float v = values[i];
        float vc = v / vmax;
        // searchsorted(edges, vc, side='right') - 1  ==  (#edges <= vc) - 1
        int bin = -1;
#pragma unroll
        for (int j = 0; j <= BINS; ++j) bin += (edges[j] <= vc) ? 1 : 0;
        bin = min(max(bin, 0), BINS - 1);
        atomicAdd(&lc[bin], 1u);
        atomicAdd(&ls[bin], v);
    }
    __syncthreads();
    if (threadIdx.x < BINS) {
        if (lc[threadIdx.x]) {
            atomicAdd(&counts[threadIdx.x], lc[threadIdx.x]);
            atomicAdd(&sums[threadIdx.x], ls[threadIdx.x]);
        }
    }

    // Fused finalization: last block to finish computes the output.
    __syncthreads();
    if (threadIdx.x == 0) {
        __threadfence();                       // release our bin atomics
        unsigned int ticket = atomicAdd(done, 1u);
        amLast = (ticket == gridDim.x - 1);
    }
    __syncthreads();
    if (amLast && threadIdx.x == 0) {
        __threadfence();                       // acquire all blocks' atomics
        int nn = 0;
        float acc = 0.f;
#pragma unroll
        for (int b = 0; b < BINS; ++b) {
            // atomic reads: same coherent path as the atomic writes (XCD-safe)
            unsigned int c = atomicAdd(&counts[b], 0u);
            float sm = atomicAdd(&sums[b], 0.0f);
            if (c > 0u) { ++nn; acc += sm / (float)c; }
        }
        float nne = (nn > 0) ? (float)nn : 1.f;
        out[0] = acc / nne;   // == sum_i weights[i] * values[i]
    }
}

extern "C" void kernel_launch(void* const* d_in, const int* in_sizes, int n_in,
                              void* d_out, int out_size, void* d_ws, size_t ws_size,
                              hipStream_t stream) {
    const float* pred = (const float*)d_in[0];
    const int* target = (const int*)d_in[1];
    float* out = (float*)d_out;

    float* values = (float*)d_ws;
    unsigned int* stats = (unsigned int*)((char*)d_ws + (size_t)N_SAMPLES * sizeof(float));
    unsigned int* vmax_bits = stats;
    unsigned int* counts = stats + 1;
    float* sums = (float*)(stats + 11);
    unsigned int* done = stats + 21;

    // zero vmax + counts + sums + done (ws is poisoned 0xAA before every call)
    hipMemsetAsync(stats, 0, 22 * sizeof(unsigned int), stream);

    values_kernel<<<N_SAMPLES / 4, 256, 0, stream>>>(pred, target, values, vmax_bits);
    hist_kernel<<<256, 256, 0, stream>>>(values, vmax_bits, counts, sums, done, out);
}

// Round 9
// 709.082 us; speedup vs baseline: 1.2985x; 1.2985x over previous
//
#include <hip/hip_runtime.h>

#define N_SAMPLES 131072
#define N_CLASSES 1000
#define BINS 10

// d_ws layout:
//   [0, N_SAMPLES) floats            : values[i] = -log_softmax(pred_i)[t_i]
//   at N_SAMPLES (as uint*):
//     slots 0..9   : counts[10] (uint)
//     slots 10..19 : sums[10] (float)
//     slot 20      : done counter (last-block pattern)

__global__ __launch_bounds__(256) void values_kernel(const float* __restrict__ pred,
                                                     const int* __restrict__ target,
                                                     float* __restrict__ values) {
    const int wave = threadIdx.x >> 6;   // 4 waves per block, 1 row per wave
    const int lane = threadIdx.x & 63;
    const int row = blockIdx.x * 4 + wave;   // grid == N_SAMPLES/4 exactly

    const float4* __restrict__ rp = (const float4*)(pred + (size_t)row * N_CLASSES);

    // All four 16B loads issue unconditionally; row has exactly 250 float4.
    // k=0..2 always in-range; k=3 tail clamps the address, values masked -INF.
    float4 r0 = rp[lane];
    float4 r1 = rp[64 + lane];
    float4 r2 = rp[128 + lane];
    const int i3 = (192 + lane < 250) ? (192 + lane) : 249;
    float4 r3 = rp[i3];

    // Target logit: wave-uniform address -> broadcast, hidden under row loads.
    const int t = target[row];
    const float xt = pred[(size_t)row * N_CLASSES + t];

    const bool v3 = (192 + lane) < 250;
    const float NEG_INF = -INFINITY;
    float r3x = v3 ? r3.x : NEG_INF;
    float r3y = v3 ? r3.y : NEG_INF;
    float r3z = v3 ? r3.z : NEG_INF;
    float r3w = v3 ? r3.w : NEG_INF;

    float m0 = fmaxf(fmaxf(r0.x, r0.y), fmaxf(r0.z, r0.w));
    float m1 = fmaxf(fmaxf(r1.x, r1.y), fmaxf(r1.z, r1.w));
    float m2 = fmaxf(fmaxf(r2.x, r2.y), fmaxf(r2.z, r2.w));
    float m3 = fmaxf(fmaxf(r3x, r3y), fmaxf(r3z, r3w));
    float lmax = fmaxf(fmaxf(m0, m1), fmaxf(m2, m3));
#pragma unroll
    for (int off = 32; off > 0; off >>= 1)
        lmax = fmaxf(lmax, __shfl_xor(lmax, off, 64));

    float s0 = __expf(r0.x - lmax) + __expf(r0.y - lmax) +
               __expf(r0.z - lmax) + __expf(r0.w - lmax);
    float s1 = __expf(r1.x - lmax) + __expf(r1.y - lmax) +
               __expf(r1.z - lmax) + __expf(r1.w - lmax);
    float s2 = __expf(r2.x - lmax) + __expf(r2.y - lmax) +
               __expf(r2.z - lmax) + __expf(r2.w - lmax);
    float s3 = __expf(r3x - lmax) + __expf(r3y - lmax) +
               __expf(r3z - lmax) + __expf(r3w - lmax);
    float s = (s0 + s1) + (s2 + s3);
#pragma unroll
    for (int off = 32; off > 0; off >>= 1)
        s += __shfl_xor(s, off, 64);

    // NO atomics here (lesson: 32768 same-address atomics serialized the
    // kernel at ~12 ns each = +250 us). Plain store only.
    if (lane == 0)
        values[row] = logf(s) + lmax - xt;   // logsumexp - x_t  (>= 0 always)
}

// 256 blocks. Each block independently scans ALL of values[] (524 KB, L2-hot)
// to compute the global max -- no cross-block communication, no spin, no
// single-address atomic storm. Then bins its own 512-row slice.
__global__ __launch_bounds__(256) void histmax_kernel(const float* __restrict__ values,
                                                      unsigned int* __restrict__ counts,
                                                      float* __restrict__ sums,
                                                      unsigned int* __restrict__ done,
                                                      float* __restrict__ out) {
    __shared__ float swm[4];
    __shared__ unsigned int lc[BINS];
    __shared__ float ls[BINS];
    __shared__ bool amLast;
    if (threadIdx.x < BINS) { lc[threadIdx.x] = 0u; ls[threadIdx.x] = 0.f; }

    // Phase A: global max, computed redundantly per block (134 MB aggregate,
    // nearly all L2/L3 hits; a few us).
    const float4* __restrict__ v4 = (const float4*)values;
    float m = 0.f;  // values >= 0
    for (int i = threadIdx.x; i < N_SAMPLES / 4; i += 256) {
        float4 r = v4[i];
        m = fmaxf(fmaxf(m, fmaxf(r.x, r.y)), fmaxf(r.z, r.w));
    }
#pragma unroll
    for (int off = 32; off > 0; off >>= 1)
        m = fmaxf(m, __shfl_xor(m, off, 64));
    if ((threadIdx.x & 63) == 0) swm[threadIdx.x >> 6] = m;
    __syncthreads();
    const float vmax = fmaxf(fmaxf(swm[0], swm[1]), fmaxf(swm[2], swm[3]));

    // Phase B: bin this block's 512-row slice (reads are L2-hot from phase A).
    float edges[BINS + 1];
#pragma unroll
    for (int j = 0; j <= BINS; ++j) edges[j] = (float)j / 10.0f;  // match jnp.arange/10
    edges[BINS] += 1e-6f;

    const int base = blockIdx.x * (N_SAMPLES / 256);   // 512 rows per block
#pragma unroll
    for (int k = 0; k < (N_SAMPLES / 256) / 256; ++k) {  // 2 iterations
        float v = values[base + k * 256 + threadIdx.x];
        float vc = v / vmax;
        // searchsorted(edges, vc, side='right') - 1  ==  (#edges <= vc) - 1
        int bin = -1;
#pragma unroll
        for (int j = 0; j <= BINS; ++j) bin += (edges[j] <= vc) ? 1 : 0;
        bin = min(max(bin, 0), BINS - 1);
        atomicAdd(&lc[bin], 1u);
        atomicAdd(&ls[bin], v);
    }
    __syncthreads();
    if (threadIdx.x < BINS) {
        if (lc[threadIdx.x]) {   // 256 blocks x <=10 atomics: ~256 per address, fine
            atomicAdd(&counts[threadIdx.x], lc[threadIdx.x]);
            atomicAdd(&sums[threadIdx.x], ls[threadIdx.x]);
        }
    }

    // Phase C: last block to finish computes the output (verified pattern).
    __syncthreads();
    if (threadIdx.x == 0) {
        __threadfence();                       // release our bin atomics
        unsigned int ticket = atomicAdd(done, 1u);
        amLast = (ticket == gridDim.x - 1);
    }
    __syncthreads();
    if (amLast && threadIdx.x == 0) {
        __threadfence();                       // acquire all blocks' atomics
        int nn = 0;
        float acc = 0.f;
#pragma unroll
        for (int b = 0; b < BINS; ++b) {
            // atomic reads: same coherent path as the atomic writes (XCD-safe)
            unsigned int c = atomicAdd(&counts[b], 0u);
            float sm = atomicAdd(&sums[b], 0.0f);
            if (c > 0u) { ++nn; acc += sm / (float)c; }
        }
        float nne = (nn > 0) ? (float)nn : 1.f;
        out[0] = acc / nne;   // == sum_i weights[i] * values[i]
    }
}

extern "C" void kernel_launch(void* const* d_in, const int* in_sizes, int n_in,
                              void* d_out, int out_size, void* d_ws, size_t ws_size,
                              hipStream_t stream) {
    const float* pred = (const float*)d_in[0];
    const int* target = (const int*)d_in[1];
    float* out = (float*)d_out;

    float* values = (float*)d_ws;
    unsigned int* stats = (unsigned int*)((char*)d_ws + (size_t)N_SAMPLES * sizeof(float));
    unsigned int* counts = stats;
    float* sums = (float*)(stats + 10);
    unsigned int* done = stats + 20;

    // zero counts + sums + done (ws is poisoned 0xAA before every call)
    hipMemsetAsync(stats, 0, 21 * sizeof(unsigned int), stream);

    values_kernel<<<N_SAMPLES / 4, 256, 0, stream>>>(pred, target, values);
    histmax_kernel<<<256, 256, 0, stream>>>(values, counts, sums, done, out);
}

// Round 10
// 678.074 us; speedup vs baseline: 1.3579x; 1.0457x over previous
//
#include <hip/hip_runtime.h>

#define N_SAMPLES 131072
#define N_CLASSES 1000
#define BINS 10

// d_ws layout:
//   [0, N_SAMPLES) floats            : values[i] = -log_softmax(pred_i)[t_i]
//   at N_SAMPLES (as uint*):
//     slot 0       : vmax bits (atomicMax on uint; values >= 0)
//     slots 1..10  : counts[10] (uint)
//     slots 11..20 : sums[10] (float)
//     slot 21      : done counter (last-block pattern)

// 2 rows per wave: 8x dwordx4 in flight per lane, two independent reduction
// chains interleaved, one float2 store. Grid = N_SAMPLES/8 blocks.
__global__ __launch_bounds__(256) void values_kernel(const float* __restrict__ pred,
                                                     const int* __restrict__ target,
                                                     float* __restrict__ values) {
    const int wave = threadIdx.x >> 6;
    const int lane = threadIdx.x & 63;
    const int row0 = (blockIdx.x * 4 + wave) * 2;   // rows row0, row0+1
    const int row1 = row0 + 1;

    const float4* __restrict__ rpA = (const float4*)(pred + (size_t)row0 * N_CLASSES);
    const float4* __restrict__ rpB = (const float4*)(pred + (size_t)row1 * N_CLASSES);

    // 8 unconditional 16B loads (row = 250 float4 exactly; k=3 clamps + -INF mask)
    const int i3 = (192 + lane < 250) ? (192 + lane) : 249;
    float4 a0 = rpA[lane];
    float4 a1 = rpA[64 + lane];
    float4 a2 = rpA[128 + lane];
    float4 a3 = rpA[i3];
    float4 b0 = rpB[lane];
    float4 b1 = rpB[64 + lane];
    float4 b2 = rpB[128 + lane];
    float4 b3 = rpB[i3];

    // Target logits: wave-uniform broadcasts, latency hidden under row loads.
    const int tA = target[row0];
    const int tB = target[row1];
    const float xtA = pred[(size_t)row0 * N_CLASSES + tA];
    const float xtB = pred[(size_t)row1 * N_CLASSES + tB];

    const bool v3 = (192 + lane) < 250;
    const float NEG_INF = -INFINITY;
    float a3x = v3 ? a3.x : NEG_INF, a3y = v3 ? a3.y : NEG_INF;
    float a3z = v3 ? a3.z : NEG_INF, a3w = v3 ? a3.w : NEG_INF;
    float b3x = v3 ? b3.x : NEG_INF, b3y = v3 ? b3.y : NEG_INF;
    float b3z = v3 ? b3.z : NEG_INF, b3w = v3 ? b3.w : NEG_INF;

    float mA0 = fmaxf(fmaxf(a0.x, a0.y), fmaxf(a0.z, a0.w));
    float mA1 = fmaxf(fmaxf(a1.x, a1.y), fmaxf(a1.z, a1.w));
    float mA2 = fmaxf(fmaxf(a2.x, a2.y), fmaxf(a2.z, a2.w));
    float mA3 = fmaxf(fmaxf(a3x, a3y), fmaxf(a3z, a3w));
    float mB0 = fmaxf(fmaxf(b0.x, b0.y), fmaxf(b0.z, b0.w));
    float mB1 = fmaxf(fmaxf(b1.x, b1.y), fmaxf(b1.z, b1.w));
    float mB2 = fmaxf(fmaxf(b2.x, b2.y), fmaxf(b2.z, b2.w));
    float mB3 = fmaxf(fmaxf(b3x, b3y), fmaxf(b3z, b3w));
    float lmaxA = fmaxf(fmaxf(mA0, mA1), fmaxf(mA2, mA3));
    float lmaxB = fmaxf(fmaxf(mB0, mB1), fmaxf(mB2, mB3));
    // Two independent shuffle chains interleaved (ILP across A/B).
#pragma unroll
    for (int off = 32; off > 0; off >>= 1) {
        lmaxA = fmaxf(lmaxA, __shfl_xor(lmaxA, off, 64));
        lmaxB = fmaxf(lmaxB, __shfl_xor(lmaxB, off, 64));
    }

    float sA0 = __expf(a0.x - lmaxA) + __expf(a0.y - lmaxA) +
                __expf(a0.z - lmaxA) + __expf(a0.w - lmaxA);
    float sA1 = __expf(a1.x - lmaxA) + __expf(a1.y - lmaxA) +
                __expf(a1.z - lmaxA) + __expf(a1.w - lmaxA);
    float sA2 = __expf(a2.x - lmaxA) + __expf(a2.y - lmaxA) +
                __expf(a2.z - lmaxA) + __expf(a2.w - lmaxA);
    float sA3 = __expf(a3x - lmaxA) + __expf(a3y - lmaxA) +
                __expf(a3z - lmaxA) + __expf(a3w - lmaxA);
    float sB0 = __expf(b0.x - lmaxB) + __expf(b0.y - lmaxB) +
                __expf(b0.z - lmaxB) + __expf(b0.w - lmaxB);
    float sB1 = __expf(b1.x - lmaxB) + __expf(b1.y - lmaxB) +
                __expf(b1.z - lmaxB) + __expf(b1.w - lmaxB);
    float sB2 = __expf(b2.x - lmaxB) + __expf(b2.y - lmaxB) +
                __expf(b2.z - lmaxB) + __expf(b2.w - lmaxB);
    float sB3 = __expf(b3x - lmaxB) + __expf(b3y - lmaxB) +
                __expf(b3z - lmaxB) + __expf(b3w - lmaxB);
    float sA = (sA0 + sA1) + (sA2 + sA3);
    float sB = (sB0 + sB1) + (sB2 + sB3);
#pragma unroll
    for (int off = 32; off > 0; off >>= 1) {
        sA += __shfl_xor(sA, off, 64);
        sB += __shfl_xor(sB, off, 64);
    }

    // Plain store only (32768 same-address atomics cost +250 us in R5).
    if (lane == 0) {
        float2 v2;
        v2.x = logf(sA) + lmaxA - xtA;   // logsumexp - x_t  (>= 0 always)
        v2.y = logf(sB) + lmaxB - xtB;
        *(float2*)(values + row0) = v2;  // row0 even -> 8B aligned
    }
}

// Baseline-proven: single grid-stride pass (524 KB total), 256 block-level
// atomicMax (~3 us). NOT a redundant per-block full scan (that cost 40 us:
// 256 x 524 KB = 134 MB served cross-XCD from L3).
__global__ __launch_bounds__(256) void max_kernel(const float* __restrict__ values,
                                                  unsigned int* __restrict__ vmax_bits) {
    __shared__ float smax[4];
    float m = 0.f;  // values >= 0
    for (int i = blockIdx.x * blockDim.x + threadIdx.x; i < N_SAMPLES;
         i += gridDim.x * blockDim.x)
        m = fmaxf(m, values[i]);
#pragma unroll
    for (int off = 32; off > 0; off >>= 1)
        m = fmaxf(m, __shfl_xor(m, off, 64));
    if ((threadIdx.x & 63) == 0) smax[threadIdx.x >> 6] = m;
    __syncthreads();
    if (threadIdx.x == 0) {
        float bm = fmaxf(fmaxf(smax[0], smax[1]), fmaxf(smax[2], smax[3]));
        atomicMax(vmax_bits, __float_as_uint(bm));  // valid: non-negative floats
    }
}

__global__ __launch_bounds__(256) void hist_kernel(const float* __restrict__ values,
                                                   const unsigned int* __restrict__ vmax_bits,
                                                   unsigned int* __restrict__ counts,
                                                   float* __restrict__ sums,
                                                   unsigned int* __restrict__ done,
                                                   float* __restrict__ out) {
    __shared__ unsigned int lc[BINS];
    __shared__ float ls[BINS];
    __shared__ bool amLast;
    if (threadIdx.x < BINS) { lc[threadIdx.x] = 0u; ls[threadIdx.x] = 0.f; }
    __syncthreads();

    const float vmax = __uint_as_float(*vmax_bits);
    float edges[BINS + 1];
#pragma unroll
    for (int j = 0; j <= BINS; ++j) edges[j] = (float)j / 10.0f;  // match jnp.arange/10
    edges[BINS] += 1e-6f;

    for (int i = blockIdx.x * blockDim.x + threadIdx.x; i < N_SAMPLES;
         i += gridDim.x * blockDim.x) {
        float v = values[i];
        float vc = v / vmax;
        // searchsorted(edges, vc, side='right') - 1  ==  (#edges <= vc) - 1
        int bin = -1;
#pragma unroll
        for (int j = 0; j <= BINS; ++j) bin += (edges[j] <= vc) ? 1 : 0;
        bin = min(max(bin, 0), BINS - 1);
        atomicAdd(&lc[bin], 1u);
        atomicAdd(&ls[bin], v);
    }
    __syncthreads();
    if (threadIdx.x < BINS) {
        if (lc[threadIdx.x]) {   // 256 blocks x <=10 atomics per address: fine
            atomicAdd(&counts[threadIdx.x], lc[threadIdx.x]);
            atomicAdd(&sums[threadIdx.x], ls[threadIdx.x]);
        }
    }

    // Fused finalization: last block to finish computes the output
    // (ticket protocol verified in R5 and R9 runs).
    __syncthreads();
    if (threadIdx.x == 0) {
        __threadfence();                       // release our bin atomics
        unsigned int ticket = atomicAdd(done, 1u);
        amLast = (ticket == gridDim.x - 1);
    }
    __syncthreads();
    if (amLast && threadIdx.x == 0) {
        __threadfence();                       // acquire all blocks' atomics
        int nn = 0;
        float acc = 0.f;
#pragma unroll
        for (int b = 0; b < BINS; ++b) {
            // atomic reads: same coherent path as the atomic writes (XCD-safe)
            unsigned int c = atomicAdd(&counts[b], 0u);
            float sm = atomicAdd(&sums[b], 0.0f);
            if (c > 0u) { ++nn; acc += sm / (float)c; }
        }
        float nne = (nn > 0) ? (float)nn : 1.f;
        out[0] = acc / nne;   // == sum_i weights[i] * values[i]
    }
}

extern "C" void kernel_launch(void* const* d_in, const int* in_sizes, int n_in,
                              void* d_out, int out_size, void* d_ws, size_t ws_size,
                              hipStream_t stream) {
    const float* pred = (const float*)d_in[0];
    const int* target = (const int*)d_in[1];
    float* out = (float*)d_out;

    float* values = (float*)d_ws;
    unsigned int* stats = (unsigned int*)((char*)d_ws + (size_t)N_SAMPLES * sizeof(float));
    unsigned int* vmax_bits = stats;
    unsigned int* counts = stats + 1;
    float* sums = (float*)(stats + 11);
    unsigned int* done = stats + 21;

    // zero vmax + counts + sums + done (ws is poisoned 0xAA before every call)
    hipMemsetAsync(stats, 0, 22 * sizeof(unsigned int), stream);

    values_kernel<<<N_SAMPLES / 8, 256, 0, stream>>>(pred, target, values);
    max_kernel<<<256, 256, 0, stream>>>(values, vmax_bits);
    hist_kernel<<<256, 256, 0, stream>>>(values, vmax_bits, counts, sums, done, out);
}